// Round 1
// baseline (218.415 us; speedup 1.0000x reference)
//
#include <hip/hip_runtime.h>
#include <hip/hip_bf16.h>

#define BATCH 512
#define DIM 256
#define NT 512
#define DEPTH 6
#define UNITS 3
#define NL 64
#define COLS (NT * DEPTH)  // 3072
#define BT 8               // batch rows per block in fused kernel

// ---------------- Kernel A: sparsemax over feature dim per (n,d) column ----
__global__ __launch_bounds__(256) void k_sparsemax(
    const float* __restrict__ logits, float* __restrict__ selT) {
  const int col = blockIdx.x;          // col = n*DEPTH + d
  const int n = col / DEPTH, d = col % DEPTH;
  const int i = threadIdx.x;

  const float z = logits[i * COLS + col];  // logits[i, n, d]

  __shared__ float s[DIM];
  __shared__ int kc[4];
  s[i] = z;
  __syncthreads();

  // bitonic sort, descending
  for (int k = 2; k <= DIM; k <<= 1) {
    for (int j = k >> 1; j > 0; j >>= 1) {
      int ixj = i ^ j;
      if (ixj > i) {
        float a = s[i], b = s[ixj];
        bool sw = ((i & k) == 0) ? (a < b) : (a > b);
        if (sw) { s[i] = b; s[ixj] = a; }
      }
      __syncthreads();
    }
  }
  const float zs = s[i];  // sorted descending value at rank i

  // inclusive cumsum (Hillis-Steele) in s
  for (int off = 1; off < DIM; off <<= 1) {
    float t = (i >= off) ? s[i - off] : 0.0f;
    __syncthreads();
    s[i] += t;
    __syncthreads();
  }
  const float cum = s[i];

  // support count k_z = sum( 1 + k*zs_k > cum_k )
  bool supp = (1.0f + (float)(i + 1) * zs) > cum;
  unsigned long long m = __ballot(supp);
  if ((i & 63) == 0) kc[i >> 6] = __popcll(m);
  __syncthreads();
  const int kz = kc[0] + kc[1] + kc[2] + kc[3];
  const float tau = (s[kz - 1] - 1.0f) / (float)kz;

  // write transposed: selT[(i*DEPTH + d)*NT + n]
  selT[(i * DEPTH + d) * NT + n] = fmaxf(z - tau, 0.0f);
}

// ---------------- Kernel C: transpose response (n,u,c) -> (u,c,n) ----------
__global__ __launch_bounds__(256) void k_transpose_resp(
    const float* __restrict__ resp, float* __restrict__ respT) {
  int idx = blockIdx.x * 256 + threadIdx.x;  // 0 .. 98303
  int n = idx / (UNITS * NL);
  int r = idx % (UNITS * NL);  // u*NL + c
  respT[r * NT + n] = resp[idx];
}

// ---------------- Kernel B: fused fv -> gates -> leaves -> output ----------
__global__ __launch_bounds__(256) void k_forest(
    const float* __restrict__ x, const float* __restrict__ selT,
    const float* __restrict__ thr, const float* __restrict__ ltemp,
    const float* __restrict__ respT, float* __restrict__ out) {
  const int tid = threadIdx.x;
  const int n = (blockIdx.x & 1) * 256 + tid;   // one tree per thread
  const int b0 = (blockIdx.x >> 1) * BT;        // 8 batch rows per block

  __shared__ float xl[BT * DIM];
#pragma unroll
  for (int k = 0; k < BT; ++k) {
    int idx = k * 256 + tid;
    xl[idx] = x[b0 * DIM + idx];  // xl[bb*DIM + i] = x[b0+bb][i]
  }
  __syncthreads();

  float acc[BT][DEPTH];
#pragma unroll
  for (int bb = 0; bb < BT; ++bb)
#pragma unroll
    for (int d = 0; d < DEPTH; ++d) acc[bb][d] = 0.0f;

  for (int i = 0; i < DIM; ++i) {
#pragma unroll
    for (int d = 0; d < DEPTH; ++d) {
      float sv = selT[(i * DEPTH + d) * NT + n];
#pragma unroll
      for (int bb = 0; bb < BT; ++bb)
        acc[bb][d] = fmaf(xl[bb * DIM + i], sv, acc[bb][d]);
    }
  }

  float th[DEPTH], et[DEPTH];
#pragma unroll
  for (int d = 0; d < DEPTH; ++d) {
    th[d] = thr[n * DEPTH + d];
    et[d] = expf(-ltemp[n * DEPTH + d]);
  }

  for (int bb = 0; bb < BT; ++bb) {
    float g0[DEPTH], g1[DEPTH];
#pragma unroll
    for (int d = 0; d < DEPTH; ++d) {
      float tl = (acc[bb][d] - th[d]) * et[d];
      float gg = fminf(fmaxf(0.5f * tl + 0.5f, 0.0f), 1.0f);  // sparsemoid(tl)
      g0[d] = gg;          // leaf bit 0 picks sparsemoid(+tl)
      g1[d] = 1.0f - gg;   // leaf bit 1 picks sparsemoid(-tl)
    }
    float t012[8], t345[8];
#pragma unroll
    for (int c = 0; c < 8; ++c) {
      t012[c] = ((c & 1) ? g1[0] : g0[0]) * ((c & 2) ? g1[1] : g0[1]) *
                ((c & 4) ? g1[2] : g0[2]);
      t345[c] = ((c & 1) ? g1[3] : g0[3]) * ((c & 2) ? g1[4] : g0[4]) *
                ((c & 4) ? g1[5] : g0[5]);
    }
    float o0 = 0.0f, o1 = 0.0f, o2 = 0.0f;
#pragma unroll
    for (int c = 0; c < NL; ++c) {
      float p = t012[c & 7] * t345[c >> 3];
      o0 = fmaf(p, respT[(0 * NL + c) * NT + n], o0);
      o1 = fmaf(p, respT[(1 * NL + c) * NT + n], o1);
      o2 = fmaf(p, respT[(2 * NL + c) * NT + n], o2);
    }
    const int b = b0 + bb;
    float* op = out + ((size_t)b * NT + n) * UNITS;
    op[0] = o0; op[1] = o1; op[2] = o2;
  }
}

extern "C" void kernel_launch(void* const* d_in, const int* in_sizes, int n_in,
                              void* d_out, int out_size, void* d_ws, size_t ws_size,
                              hipStream_t stream) {
  const float* x    = (const float*)d_in[0];  // (512, 256)
  const float* fsl  = (const float*)d_in[1];  // (256, 512, 6)
  const float* thr  = (const float*)d_in[2];  // (512, 6)
  const float* lt   = (const float*)d_in[3];  // (512, 6)
  const float* resp = (const float*)d_in[4];  // (512, 3, 64)
  float* out = (float*)d_out;                 // (512, 512, 3)

  float* ws = (float*)d_ws;
  float* selT  = ws;                       // (256*6, 512) = 786432 floats
  float* respT = ws + (size_t)DIM * DEPTH * NT;  // (3*64, 512) = 98304 floats

  k_sparsemax<<<COLS, 256, 0, stream>>>(fsl, selT);
  k_transpose_resp<<<(NT * UNITS * NL) / 256, 256, 0, stream>>>(resp, respT);
  k_forest<<<(BATCH / BT) * (NT / 256), 256, 0, stream>>>(x, selT, thr, lt,
                                                          respT, out);
}

// Round 2
// 121.676 us; speedup vs baseline: 1.7951x; 1.7951x over previous
//
#include <hip/hip_runtime.h>
#include <hip/hip_bf16.h>

#define BATCH 512
#define DIM 256
#define NT 512
#define DEPTH 6
#define UNITS 3
#define NL 64
#define COLS (NT * DEPTH)  // 3072

// ---------------- Kernel A: sparsemax via Newton, one wave per (n,d) column
// g(tau) = sum_i relu(z_i - tau) - 1 is convex, piecewise-linear, decreasing.
// From tau0 = max(z) - 1 (g >= 0), Newton tau += g/k converges monotonically
// and exactly once in the correct segment. No sort, no barriers.
__global__ __launch_bounds__(256) void k_sparsemax2(
    const float* __restrict__ logits, float* __restrict__ selT) {
  const int wv = threadIdx.x >> 6, lane = threadIdx.x & 63;
  const int col = blockIdx.x * 4 + wv;  // col = n*DEPTH + d

  float z[4];
#pragma unroll
  for (int j = 0; j < 4; ++j) z[j] = logits[(j * 64 + lane) * COLS + col];

  float m = fmaxf(fmaxf(z[0], z[1]), fmaxf(z[2], z[3]));
#pragma unroll
  for (int o = 32; o > 0; o >>= 1) m = fmaxf(m, __shfl_xor(m, o, 64));

  float tau = m - 1.0f;
  for (int it = 0; it < 24; ++it) {
    float s = 0.0f, k = 0.0f;
#pragma unroll
    for (int j = 0; j < 4; ++j) {
      float d = z[j] - tau;
      if (d > 0.0f) { s += d; k += 1.0f; }
    }
#pragma unroll
    for (int o = 32; o > 0; o >>= 1) {
      s += __shfl_xor(s, o, 64);
      k += __shfl_xor(k, o, 64);
    }
    tau += (s - 1.0f) / k;  // k >= 1 always (tau < max)
  }

  const int n = col / DEPTH, d = col % DEPTH;
#pragma unroll
  for (int j = 0; j < 4; ++j) {
    selT[((j * 64 + lane) * NT + n) * DEPTH + d] = fmaxf(z[j] - tau, 0.0f);
  }
}

// ---------------- Kernel C: transpose response (n,u,c) -> (u,c,n) ----------
__global__ __launch_bounds__(256) void k_transpose_resp(
    const float* __restrict__ resp, float* __restrict__ respT) {
  int idx = blockIdx.x * 256 + threadIdx.x;  // 0 .. 98303
  int n = idx / (UNITS * NL);
  int r = idx % (UNITS * NL);  // u*NL + c
  respT[r * NT + n] = resp[idx];
}

// ---------------- Kernel B: fused fv -> gates -> leaves -> output ----------
// Block = 256 threads = 4 wave-groups x 64 trees; each thread owns 1 tree and
// 2 batch rows; block covers 64 trees x 8 batch rows. Grid = 8 tree-tiles x
// 64 batch-tiles = 512 blocks. blockIdx&7 = tree-tile -> round-robin XCD
// dispatch pins each selT panel (~512KB) into one XCD's L2.
__global__ __launch_bounds__(256) void k_forest2(
    const float* __restrict__ x, const float* __restrict__ selT,
    const float* __restrict__ thr, const float* __restrict__ ltemp,
    const float* __restrict__ respT, float* __restrict__ out) {
  const int tid = threadIdx.x;
  const int nloc = tid & 63, bg = tid >> 6;  // bg = 0..3
  const int tt = blockIdx.x & 7, bt = blockIdx.x >> 3;
  const int n = tt * 64 + nloc;
  const int b0 = bt * 8;

  __shared__ float xl[8 * DIM];
#pragma unroll
  for (int k = 0; k < 8; ++k) xl[k * 256 + tid] = x[b0 * DIM + k * 256 + tid];
  __syncthreads();

  const float* xr0 = &xl[(bg * 2 + 0) * DIM];
  const float* xr1 = &xl[(bg * 2 + 1) * DIM];

  float a0[DEPTH], a1[DEPTH];
#pragma unroll
  for (int d = 0; d < DEPTH; ++d) { a0[d] = 0.0f; a1[d] = 0.0f; }

  for (int i = 0; i < DIM; ++i) {
    const float2* sp = (const float2*)&selT[(i * NT + n) * DEPTH];
    float2 s0 = sp[0], s1 = sp[1], s2 = sp[2];
    float xa = xr0[i], xb = xr1[i];
    a0[0] = fmaf(xa, s0.x, a0[0]); a1[0] = fmaf(xb, s0.x, a1[0]);
    a0[1] = fmaf(xa, s0.y, a0[1]); a1[1] = fmaf(xb, s0.y, a1[1]);
    a0[2] = fmaf(xa, s1.x, a0[2]); a1[2] = fmaf(xb, s1.x, a1[2]);
    a0[3] = fmaf(xa, s1.y, a0[3]); a1[3] = fmaf(xb, s1.y, a1[3]);
    a0[4] = fmaf(xa, s2.x, a0[4]); a1[4] = fmaf(xb, s2.x, a1[4]);
    a0[5] = fmaf(xa, s2.y, a0[5]); a1[5] = fmaf(xb, s2.y, a1[5]);
  }

  float th[DEPTH], et[DEPTH];
#pragma unroll
  for (int d = 0; d < DEPTH; ++d) {
    th[d] = thr[n * DEPTH + d];
    et[d] = expf(-ltemp[n * DEPTH + d]);
  }

  // gates -> per-row half-leaf product tables
  float t012[2][8], t345[2][8];
#pragma unroll
  for (int r = 0; r < 2; ++r) {
    float g0[DEPTH], g1[DEPTH];
#pragma unroll
    for (int d = 0; d < DEPTH; ++d) {
      float av = r ? a1[d] : a0[d];
      float tl = (av - th[d]) * et[d];
      float gg = fminf(fmaxf(0.5f * tl + 0.5f, 0.0f), 1.0f);  // sparsemoid
      g0[d] = gg;         // leaf bit 0 -> sparsemoid(+tl)
      g1[d] = 1.0f - gg;  // leaf bit 1 -> sparsemoid(-tl)
    }
#pragma unroll
    for (int c = 0; c < 8; ++c) {
      t012[r][c] = ((c & 1) ? g1[0] : g0[0]) * ((c & 2) ? g1[1] : g0[1]) *
                   ((c & 4) ? g1[2] : g0[2]);
      t345[r][c] = ((c & 1) ? g1[3] : g0[3]) * ((c & 2) ? g1[4] : g0[4]) *
                   ((c & 4) ? g1[5] : g0[5]);
    }
  }

  // leaf products x response; resp loaded once per c, reused across rows
  float o00 = 0, o01 = 0, o02 = 0, o10 = 0, o11 = 0, o12 = 0;
#pragma unroll
  for (int c = 0; c < NL; ++c) {
    float r0 = respT[(0 * NL + c) * NT + n];
    float r1 = respT[(1 * NL + c) * NT + n];
    float r2 = respT[(2 * NL + c) * NT + n];
    float p0 = t012[0][c & 7] * t345[0][c >> 3];
    float p1 = t012[1][c & 7] * t345[1][c >> 3];
    o00 = fmaf(p0, r0, o00); o01 = fmaf(p0, r1, o01); o02 = fmaf(p0, r2, o02);
    o10 = fmaf(p1, r0, o10); o11 = fmaf(p1, r1, o11); o12 = fmaf(p1, r2, o12);
  }

  const int ba = b0 + bg * 2, bb = ba + 1;
  float* oa = out + ((size_t)ba * NT + n) * UNITS;
  float* ob = out + ((size_t)bb * NT + n) * UNITS;
  oa[0] = o00; oa[1] = o01; oa[2] = o02;
  ob[0] = o10; ob[1] = o11; ob[2] = o12;
}

extern "C" void kernel_launch(void* const* d_in, const int* in_sizes, int n_in,
                              void* d_out, int out_size, void* d_ws, size_t ws_size,
                              hipStream_t stream) {
  const float* x    = (const float*)d_in[0];  // (512, 256)
  const float* fsl  = (const float*)d_in[1];  // (256, 512, 6)
  const float* thr  = (const float*)d_in[2];  // (512, 6)
  const float* lt   = (const float*)d_in[3];  // (512, 6)
  const float* resp = (const float*)d_in[4];  // (512, 3, 64)
  float* out = (float*)d_out;                 // (512, 512, 3)

  float* ws = (float*)d_ws;
  float* selT  = ws;                              // (256, 512, 6) = 786432 f
  float* respT = ws + (size_t)DIM * NT * DEPTH;   // (3*64, 512)   =  98304 f

  k_sparsemax2<<<COLS / 4, 256, 0, stream>>>(fsl, selT);
  k_transpose_resp<<<(NT * UNITS * NL) / 256, 256, 0, stream>>>(resp, respT);
  k_forest2<<<512, 256, 0, stream>>>(x, selT, thr, lt, respT, out);
}

// Round 3
// 99.897 us; speedup vs baseline: 2.1864x; 1.2180x over previous
//
#include <hip/hip_runtime.h>
#include <hip/hip_bf16.h>

#define BATCH 512
#define DIM 256
#define NT 512
#define DEPTH 6
#define UNITS 3
#define NL 64
#define COLS (NT * DEPTH)  // 3072
#define KMAX 32            // max stored sparsemax support per column

// ws layout:
//   int2   lists[DEPTH][KMAX][NT]   (768 KB)  sparse (idx,val) per column
//   int    cnt  [DEPTH][NT]         ( 12 KB)
//   float4 resp4[NL][NT]            (512 KB)  response, u in .x/.y/.z

// ---- Kernel A: sparsemax (Newton) + sparse compaction + resp transpose ----
// Blocks 0..767: 4 waves x 1 column each (3072 columns).
// Blocks 768..1151: transpose response (n,u,c) -> resp4[c][n].u
__global__ __launch_bounds__(256) void k_prep(
    const float* __restrict__ logits, const float* __restrict__ resp,
    int2* __restrict__ lists, int* __restrict__ cnt,
    float4* __restrict__ resp4) {
  if (blockIdx.x >= 768) {
    int idx = (blockIdx.x - 768) * 256 + threadIdx.x;  // 0..98303
    int n = idx / (UNITS * NL);
    int r = idx % (UNITS * NL);
    int u = r / NL, c = r % NL;
    ((float*)&resp4[c * NT + n])[u] = resp[idx];
    return;
  }
  const int wv = threadIdx.x >> 6, lane = threadIdx.x & 63;
  const int col = blockIdx.x * 4 + wv;  // col = n*DEPTH + d
  const int n = col / DEPTH, d = col % DEPTH;

  float z[4];
#pragma unroll
  for (int j = 0; j < 4; ++j) z[j] = logits[(j * 64 + lane) * COLS + col];

  float m = fmaxf(fmaxf(z[0], z[1]), fmaxf(z[2], z[3]));
#pragma unroll
  for (int o = 32; o > 0; o >>= 1) m = fmaxf(m, __shfl_xor(m, o, 64));

  // Newton on g(tau)=sum relu(z-tau)-1: convex piecewise-linear, monotone
  // convergence from tau0=max-1; support k>=1 guaranteed (tau stays < max).
  float tau = m - 1.0f;
  for (int it = 0; it < 16; ++it) {
    float s = 0.0f, k = 0.0f;
#pragma unroll
    for (int j = 0; j < 4; ++j) {
      float dd = z[j] - tau;
      if (dd > 0.0f) { s += dd; k += 1.0f; }
    }
#pragma unroll
    for (int o = 32; o > 0; o >>= 1) {
      s += __shfl_xor(s, o, 64);
      k += __shfl_xor(k, o, 64);
    }
    float delta = (s - 1.0f) / k;
    tau += delta;
    if (fabsf(delta) < 1e-7f) break;  // wave-uniform (s,k fully reduced)
  }

  // compact nonzeros (order irrelevant: consumer sums)
  int base = 0;
#pragma unroll
  for (int j = 0; j < 4; ++j) {
    bool nz = z[j] > tau;
    unsigned long long mk = __ballot(nz);
    int pos = base + __popcll(mk & ((1ull << lane) - 1ull));
    if (nz && pos < KMAX)
      lists[(d * KMAX + pos) * NT + n] =
          make_int2(j * 64 + lane, __float_as_int(z[j] - tau));
    base += __popcll(mk);
  }
  if (lane == 0) cnt[d * NT + n] = min(base, KMAX);
}

// ---- Kernel B: sparse fv -> gates -> leaves -> output ---------------------
// Block = 256 thr = 4 waves x 64 trees; thread owns 1 tree, 2 batch rows.
// Grid = 8 tree-tiles x 64 batch-tiles = 512 blocks; blockIdx&7 = tree-tile
// round-robins XCDs so each tile's lists/resp4 panel stays hot in one L2.
__global__ __launch_bounds__(256) void k_forest3(
    const float* __restrict__ x, const int2* __restrict__ lists,
    const int* __restrict__ cnt, const float* __restrict__ thr,
    const float* __restrict__ ltemp, const float4* __restrict__ resp4,
    float* __restrict__ out) {
  const int tid = threadIdx.x;
  const int nloc = tid & 63, bg = tid >> 6;
  const int tt = blockIdx.x & 7, bt = blockIdx.x >> 3;
  const int n = tt * 64 + nloc;
  const int b0 = bt * 8;

  __shared__ float xl[8 * DIM];
#pragma unroll
  for (int k = 0; k < 8; ++k) xl[k * 256 + tid] = x[b0 * DIM + k * 256 + tid];
  __syncthreads();

  const float* xr0 = &xl[(bg * 2 + 0) * DIM];
  const float* xr1 = &xl[(bg * 2 + 1) * DIM];

  float fv0[DEPTH], fv1[DEPTH];
#pragma unroll
  for (int d = 0; d < DEPTH; ++d) { fv0[d] = 0.0f; fv1[d] = 0.0f; }

#pragma unroll
  for (int d = 0; d < DEPTH; ++d) {
    const int c = cnt[d * NT + n];
    for (int j = 0; j < c; ++j) {           // coalesced over n per (d,j)
      int2 e = lists[(d * KMAX + j) * NT + n];
      float v = __int_as_float(e.y);
      fv0[d] = fmaf(v, xr0[e.x], fv0[d]);   // LDS gather
      fv1[d] = fmaf(v, xr1[e.x], fv1[d]);
    }
  }

  float th[DEPTH], et[DEPTH];
#pragma unroll
  for (int d = 0; d < DEPTH; ++d) {
    th[d] = thr[n * DEPTH + d];
    et[d] = expf(-ltemp[n * DEPTH + d]);
  }

  float t012[2][8], t345[2][8];
#pragma unroll
  for (int r = 0; r < 2; ++r) {
    float g0[DEPTH], g1[DEPTH];
#pragma unroll
    for (int d = 0; d < DEPTH; ++d) {
      float av = r ? fv1[d] : fv0[d];
      float tl = (av - th[d]) * et[d];
      float gg = fminf(fmaxf(0.5f * tl + 0.5f, 0.0f), 1.0f);  // sparsemoid
      g0[d] = gg;         // leaf bit 0 -> sparsemoid(+tl)
      g1[d] = 1.0f - gg;  // leaf bit 1 -> sparsemoid(-tl)
    }
#pragma unroll
    for (int c = 0; c < 8; ++c) {
      t012[r][c] = ((c & 1) ? g1[0] : g0[0]) * ((c & 2) ? g1[1] : g0[1]) *
                   ((c & 4) ? g1[2] : g0[2]);
      t345[r][c] = ((c & 1) ? g1[3] : g0[3]) * ((c & 2) ? g1[4] : g0[4]) *
                   ((c & 4) ? g1[5] : g0[5]);
    }
  }

  float o00 = 0, o01 = 0, o02 = 0, o10 = 0, o11 = 0, o12 = 0;
#pragma unroll
  for (int c = 0; c < NL; ++c) {
    float4 rr = resp4[c * NT + n];          // 16B aligned, coalesced
    float p0 = t012[0][c & 7] * t345[0][c >> 3];
    float p1 = t012[1][c & 7] * t345[1][c >> 3];
    o00 = fmaf(p0, rr.x, o00); o01 = fmaf(p0, rr.y, o01); o02 = fmaf(p0, rr.z, o02);
    o10 = fmaf(p1, rr.x, o10); o11 = fmaf(p1, rr.y, o11); o12 = fmaf(p1, rr.z, o12);
  }

  const int ba = b0 + bg * 2, bb = ba + 1;
  float* oa = out + ((size_t)ba * NT + n) * UNITS;
  float* ob = out + ((size_t)bb * NT + n) * UNITS;
  oa[0] = o00; oa[1] = o01; oa[2] = o02;
  ob[0] = o10; ob[1] = o11; ob[2] = o12;
}

extern "C" void kernel_launch(void* const* d_in, const int* in_sizes, int n_in,
                              void* d_out, int out_size, void* d_ws, size_t ws_size,
                              hipStream_t stream) {
  const float* x    = (const float*)d_in[0];  // (512, 256)
  const float* fsl  = (const float*)d_in[1];  // (256, 512, 6)
  const float* thr  = (const float*)d_in[2];  // (512, 6)
  const float* lt   = (const float*)d_in[3];  // (512, 6)
  const float* resp = (const float*)d_in[4];  // (512, 3, 64)
  float* out = (float*)d_out;                 // (512, 512, 3)

  int2* lists = (int2*)d_ws;                         // 6*32*512 int2 = 768 KB
  int* cnt = (int*)(lists + DEPTH * KMAX * NT);      // 3072 int   =  12 KB
  float4* resp4 =
      (float4*)((char*)d_ws + DEPTH * KMAX * NT * 8 + DEPTH * NT * 4);  // 512 KB

  k_prep<<<768 + 384, 256, 0, stream>>>(fsl, resp, lists, cnt, resp4);
  k_forest3<<<512, 256, 0, stream>>>(x, lists, cnt, thr, lt, resp4, out);
}

// Round 4
// 94.230 us; speedup vs baseline: 2.3179x; 1.0601x over previous
//
#include <hip/hip_runtime.h>
#include <hip/hip_bf16.h>

#define BATCH 512
#define DIM 256
#define NT 512
#define DEPTH 6
#define UNITS 3
#define NL 64
#define COLS (NT * DEPTH)  // 3072
#define KMAX 32            // padded sparse entries per column (zero-filled)

// ws layout (floats):
//   logitsT [COLS][DIM]            786432   coalesced sparsemax input
//   resp4   [NL][NT] float4        131072   response, u in .x/.y/.z
//   val4    [DEPTH][8][NT] float4   98304   packed sparse values (4/group)
//   idx4    [DEPTH][8][NT] uint     24576   packed sparse indices (4x u8)
//   cnt     [DEPTH][NT] int          3072
//   pth     [DEPTH][NT]              3072   thresholds, [d][n] layout
//   pet     [DEPTH][NT]              3072   exp(-log_temp), [d][n] layout

// ---- Kernel 1: pack/transpose everything ----------------------------------
// blocks 0..191   : transpose logits (256 x 3072) -> logitsT (3072 x 256)
// blocks 192..575 : transpose response (n,u,c) -> resp4[c][n].u
// blocks 576..587 : pack thr / exp(-ltemp) into [d][n]
__global__ __launch_bounds__(256) void k_pack(
    const float* __restrict__ logits, const float* __restrict__ resp,
    const float* __restrict__ thr, const float* __restrict__ ltemp,
    float* __restrict__ logitsT, float4* __restrict__ resp4,
    float* __restrict__ pth, float* __restrict__ pet) {
  const int bid = blockIdx.x, tid = threadIdx.x;
  if (bid < 192) {
    // 64x64 tile transpose; all global accesses 256B-coalesced per wave
    const int c0 = (bid % 48) * 64, r0 = (bid / 48) * 64;
    __shared__ float tile[64][65];
#pragma unroll
    for (int e = tid; e < 4096; e += 256) {
      int r = e >> 6, c = e & 63;
      tile[r][c] = logits[(r0 + r) * COLS + c0 + c];
    }
    __syncthreads();
#pragma unroll
    for (int e = tid; e < 4096; e += 256) {
      int c = e >> 6, r = e & 63;
      logitsT[(c0 + c) * DIM + r0 + r] = tile[r][c];
    }
  } else if (bid < 576) {
    int idx = (bid - 192) * 256 + tid;  // 0..98303
    int n = idx / (UNITS * NL);
    int r = idx % (UNITS * NL);
    int u = r / NL, c = r % NL;
    ((float*)&resp4[c * NT + n])[u] = resp[idx];
  } else {
    int idx = (bid - 576) * 256 + tid;  // 0..3071
    int n = idx / DEPTH, d = idx % DEPTH;
    pth[d * NT + n] = thr[idx];
    pet[d * NT + n] = expf(-ltemp[idx]);
  }
}

// ---- Kernel 2: sparsemax (Newton) + packed compaction ---------------------
// One wave per (n,d) column; coalesced loads from logitsT.
__global__ __launch_bounds__(256) void k_sel(
    const float* __restrict__ logitsT, float4* __restrict__ val4,
    unsigned int* __restrict__ idx4, int* __restrict__ cnt) {
  const int wv = threadIdx.x >> 6, lane = threadIdx.x & 63;
  const int col = blockIdx.x * 4 + wv;  // col = n*DEPTH + d
  const int n = col / DEPTH, d = col % DEPTH;

  float z[4];
#pragma unroll
  for (int j = 0; j < 4; ++j) z[j] = logitsT[col * DIM + j * 64 + lane];

  float m = fmaxf(fmaxf(z[0], z[1]), fmaxf(z[2], z[3]));
#pragma unroll
  for (int o = 32; o > 0; o >>= 1) m = fmaxf(m, __shfl_xor(m, o, 64));

  // Newton on g(tau)=sum relu(z-tau)-1: convex piecewise-linear; from
  // tau0=max-1 (g>=0) converges monotonically, exact once in right segment.
  float tau = m - 1.0f;
  for (int it = 0; it < 16; ++it) {
    float s = 0.0f, k = 0.0f;
#pragma unroll
    for (int j = 0; j < 4; ++j) {
      float dd = z[j] - tau;
      if (dd > 0.0f) { s += dd; k += 1.0f; }
    }
#pragma unroll
    for (int o = 32; o > 0; o >>= 1) {
      s += __shfl_xor(s, o, 64);
      k += __shfl_xor(k, o, 64);
    }
    float delta = (s - 1.0f) / k;  // k>=1 always (tau < max)
    tau += delta;
    if (fabsf(delta) < 1e-7f) break;  // wave-uniform
  }

  // compact nonzeros into packed SoA groups of 4 (order-free: consumer sums)
  float* vbase = (float*)val4;           // component-addressable
  unsigned char* ibase = (unsigned char*)idx4;
  int base = 0;
#pragma unroll
  for (int j = 0; j < 4; ++j) {
    bool nz = z[j] > tau;
    unsigned long long mk = __ballot(nz);
    int pos = base + __popcll(mk & ((1ull << lane) - 1ull));
    if (nz && pos < KMAX) {
      int slot = ((d * 8 + (pos >> 2)) * NT + n) * 4 + (pos & 3);
      vbase[slot] = z[j] - tau;
      ibase[slot] = (unsigned char)(j * 64 + lane);
    }
    base += __popcll(mk);
  }
  const int cc = min(base, KMAX);
  // zero-fill padding so any loop bound >= cc is valid downstream
  if (lane >= cc && lane < KMAX) {
    int slot = ((d * 8 + (lane >> 2)) * NT + n) * 4 + (lane & 3);
    vbase[slot] = 0.0f;
    ibase[slot] = 0;
  }
  if (lane == 0) cnt[d * NT + n] = cc;
}

// ---- Kernel 3: sparse fv -> gates -> leaves -> output ---------------------
// Block = 256 thr = 4 row-groups x 64 trees; thread owns 1 tree, 2 rows.
// Grid = 8 tree-tiles x 64 batch-tiles; blockIdx&7 = tree-tile (XCD spread).
__global__ __launch_bounds__(256) void k_forest4(
    const float* __restrict__ x, const float4* __restrict__ val4,
    const unsigned int* __restrict__ idx4, const int* __restrict__ cnt,
    const float* __restrict__ pth, const float* __restrict__ pet,
    const float4* __restrict__ resp4, float* __restrict__ out) {
  const int tid = threadIdx.x;
  const int nloc = tid & 63, bg = tid >> 6;
  const int tt = blockIdx.x & 7, bt = blockIdx.x >> 3;
  const int n = tt * 64 + nloc;
  const int b0 = bt * 8;

  __shared__ float xl[8 * DIM];
#pragma unroll
  for (int k = 0; k < 8; ++k) xl[k * 256 + tid] = x[b0 * DIM + k * 256 + tid];
  __syncthreads();

  const float* xr0 = &xl[(bg * 2 + 0) * DIM];
  const float* xr1 = &xl[(bg * 2 + 1) * DIM];

  float fv0[DEPTH], fv1[DEPTH];
#pragma unroll
  for (int d = 0; d < DEPTH; ++d) { fv0[d] = 0.0f; fv1[d] = 0.0f; }

#pragma unroll
  for (int d = 0; d < DEPTH; ++d) {
    int mc = cnt[d * NT + n];  // coalesced over lanes
#pragma unroll
    for (int o = 32; o > 0; o >>= 1) mc = max(mc, __shfl_xor(mc, o, 64));
    const int nq = (mc + 3) >> 2;  // wave-uniform group count
#pragma unroll
    for (int jq = 0; jq < 8; ++jq) {
      if (jq < nq) {  // uniform branch, independent of loads -> all issue
        float4 v = val4[(d * 8 + jq) * NT + n];       // coalesced 16B
        unsigned int ip = idx4[(d * 8 + jq) * NT + n];  // coalesced 4B
        int i0 = ip & 255, i1 = (ip >> 8) & 255;
        int i2 = (ip >> 16) & 255, i3 = ip >> 24;
        fv0[d] = fmaf(v.x, xr0[i0], fv0[d]); fv1[d] = fmaf(v.x, xr1[i0], fv1[d]);
        fv0[d] = fmaf(v.y, xr0[i1], fv0[d]); fv1[d] = fmaf(v.y, xr1[i1], fv1[d]);
        fv0[d] = fmaf(v.z, xr0[i2], fv0[d]); fv1[d] = fmaf(v.z, xr1[i2], fv1[d]);
        fv0[d] = fmaf(v.w, xr0[i3], fv0[d]); fv1[d] = fmaf(v.w, xr1[i3], fv1[d]);
      }
    }
  }

  float th[DEPTH], et[DEPTH];
#pragma unroll
  for (int d = 0; d < DEPTH; ++d) {
    th[d] = pth[d * NT + n];  // coalesced
    et[d] = pet[d * NT + n];
  }

  float t012[2][8], t345[2][8];
#pragma unroll
  for (int r = 0; r < 2; ++r) {
    float g0[DEPTH], g1[DEPTH];
#pragma unroll
    for (int d = 0; d < DEPTH; ++d) {
      float av = r ? fv1[d] : fv0[d];
      float tl = (av - th[d]) * et[d];
      float gg = fminf(fmaxf(0.5f * tl + 0.5f, 0.0f), 1.0f);  // sparsemoid
      g0[d] = gg;         // leaf bit 0 -> sparsemoid(+tl)
      g1[d] = 1.0f - gg;  // leaf bit 1 -> sparsemoid(-tl)
    }
#pragma unroll
    for (int c = 0; c < 8; ++c) {
      t012[r][c] = ((c & 1) ? g1[0] : g0[0]) * ((c & 2) ? g1[1] : g0[1]) *
                   ((c & 4) ? g1[2] : g0[2]);
      t345[r][c] = ((c & 1) ? g1[3] : g0[3]) * ((c & 2) ? g1[4] : g0[4]) *
                   ((c & 4) ? g1[5] : g0[5]);
    }
  }

  float o00 = 0, o01 = 0, o02 = 0, o10 = 0, o11 = 0, o12 = 0;
#pragma unroll
  for (int c = 0; c < NL; ++c) {
    float4 rr = resp4[c * NT + n];  // coalesced 16B, L2-resident
    float p0 = t012[0][c & 7] * t345[0][c >> 3];
    float p1 = t012[1][c & 7] * t345[1][c >> 3];
    o00 = fmaf(p0, rr.x, o00); o01 = fmaf(p0, rr.y, o01); o02 = fmaf(p0, rr.z, o02);
    o10 = fmaf(p1, rr.x, o10); o11 = fmaf(p1, rr.y, o11); o12 = fmaf(p1, rr.z, o12);
  }

  const int ba = b0 + bg * 2, bb = ba + 1;
  float* oa = out + ((size_t)ba * NT + n) * UNITS;
  float* ob = out + ((size_t)bb * NT + n) * UNITS;
  oa[0] = o00; oa[1] = o01; oa[2] = o02;
  ob[0] = o10; ob[1] = o11; ob[2] = o12;
}

extern "C" void kernel_launch(void* const* d_in, const int* in_sizes, int n_in,
                              void* d_out, int out_size, void* d_ws, size_t ws_size,
                              hipStream_t stream) {
  const float* x    = (const float*)d_in[0];  // (512, 256)
  const float* fsl  = (const float*)d_in[1];  // (256, 512, 6)
  const float* thr  = (const float*)d_in[2];  // (512, 6)
  const float* lt   = (const float*)d_in[3];  // (512, 6)
  const float* resp = (const float*)d_in[4];  // (512, 3, 64)
  float* out = (float*)d_out;                 // (512, 512, 3)

  float* ws = (float*)d_ws;
  float*        logitsT = ws;                                  // 786432 f
  float4*       resp4   = (float4*)(ws + 786432);              // 131072 f
  float4*       val4    = (float4*)(ws + 917504);              //  98304 f
  unsigned int* idx4    = (unsigned int*)(ws + 1015808);       //  24576 f
  int*          cnt     = (int*)(ws + 1040384);                //   3072 f
  float*        pth     = ws + 1043456;                        //   3072 f
  float*        pet     = ws + 1046528;                        //   3072 f

  k_pack<<<588, 256, 0, stream>>>(fsl, resp, thr, lt, logitsT, resp4, pth, pet);
  k_sel<<<COLS / 4, 256, 0, stream>>>(logitsT, val4, idx4, cnt);
  k_forest4<<<512, 256, 0, stream>>>(x, val4, idx4, cnt, pth, pet, resp4, out);
}